// Round 7
// baseline (86.584 us; speedup 1.0000x reference)
//
#include <hip/hip_runtime.h>
#include <math.h>

#define NATOMS   4096
#define NRBF     16
#define NHID     64
#define CUTOFF2  25.0f
// ETA = 0.5*(5.0-0.5)/16 = 0.140625 ; 1/(2*ETA^2)
#define INV_2ETA2 25.283950617283951f
#define PI_OVER_CUTOFF 0.62831853071795865f  // pi / 5
#define CAP      96     // per-i neighbor capacity (mean ~33, >8 sigma)

// 512 blocks x 8 i-atoms (2 per wave). ALL 4096 positions staged once as
// SoA in LDS (48 KB, one barrier). Each lane reads 4 j-atoms (3x
// ds_read_b128) serving BOTH i-atoms (2x amortization). Ballot+prefix
// compaction, branch-guarded (skip mbcnt/store when no lane hits, ~60% of
// groups). Dense transposed RBF per i; per-wave MLP per i; per-block sum
// -> ws[bid]; single-wave reduce kernel -> out[0].
__global__ __launch_bounds__(256) void short_range_kernel(
    const float* __restrict__ pos,
    const float* __restrict__ centers,
    const float* __restrict__ W1, const float* __restrict__ b1,
    const float* __restrict__ W2, const float* __restrict__ b2,
    const float* __restrict__ W3,
    float* __restrict__ ws)
{
    __shared__ float sx[NATOMS], sy[NATOMS], sz[NATOMS];  // 48 KB SoA
    __shared__ float sdist[4][2][CAP];                    // 3 KB
    __shared__ float s_h1[4][NHID];                       // 1 KB
    __shared__ float s_e[4][2];

    const int tid  = threadIdx.x;
    const int lane = tid & 63;
    const int wave = tid >> 6;
    const int i0   = blockIdx.x * 8 + wave * 2;   // wave's two atoms: i0, i0+1

    const float xi0 = pos[3 * i0 + 0];
    const float yi0 = pos[3 * i0 + 1];
    const float zi0 = pos[3 * i0 + 2];
    const float xi1 = pos[3 * i0 + 3];
    const float yi1 = pos[3 * i0 + 4];
    const float zi1 = pos[3 * i0 + 5];

    // ---- stage all 4096 atoms as SoA: thread-group g owns atoms 4g..4g+3 ----
    const float4* src = (const float4*)pos;
#pragma unroll
    for (int r = 0; r < 4; ++r) {
        const int g = tid + 256 * r;
        const float4 v0 = src[3 * g + 0];  // x0 y0 z0 x1
        const float4 v1 = src[3 * g + 1];  // y1 z1 x2 y2
        const float4 v2 = src[3 * g + 2];  // z2 x3 y3 z3
        *(float4*)&sx[4 * g] = make_float4(v0.x, v0.w, v1.z, v2.y);
        *(float4*)&sy[4 * g] = make_float4(v0.y, v1.x, v1.w, v2.z);
        *(float4*)&sz[4 * g] = make_float4(v0.z, v1.y, v2.x, v2.w);
    }
    __syncthreads();

    // ---- sieve: 16 groups; lane reads 4 j-atoms, serves both i-atoms ----
    int base0 = 0, base1 = 0;
#pragma unroll 4
    for (int ug = 0; ug < 16; ++ug) {
        const int a = ug * 256 + 4 * lane;
        const float4 vx = *(const float4*)&sx[a];
        const float4 vy = *(const float4*)&sy[a];
        const float4 vz = *(const float4*)&sz[a];
#pragma unroll
        for (int u = 0; u < 4; ++u) {
            const float px = ((const float*)&vx)[u];
            const float py = ((const float*)&vy)[u];
            const float pz = ((const float*)&vz)[u];
            {   // i0
                const float dx = px - xi0, dy = py - yi0, dz = pz - zi0;
                const float sq = dx * dx + dy * dy + dz * dz;
                const bool pass = (sq > 0.0f) && (sq < CUTOFF2);
                const unsigned long long m = __ballot(pass);
                if (m) {  // wave-uniform: skip compaction when group is empty
                    if (pass) {
                        const int slot = base0 + (int)__popcll(m & ((1ull << lane) - 1ull));
                        if (slot < CAP) sdist[wave][0][slot] = sqrtf(sq);
                    }
                    base0 += (int)__popcll(m);
                }
            }
            {   // i1
                const float dx = px - xi1, dy = py - yi1, dz = pz - zi1;
                const float sq = dx * dx + dy * dy + dz * dz;
                const bool pass = (sq > 0.0f) && (sq < CUTOFF2);
                const unsigned long long m = __ballot(pass);
                if (m) {
                    if (pass) {
                        const int slot = base1 + (int)__popcll(m & ((1ull << lane) - 1ull));
                        if (slot < CAP) sdist[wave][1][slot] = sqrtf(sq);
                    }
                    base1 += (int)__popcll(m);
                }
            }
        }
    }

    // ---- dense RBF, transposed: entry = e0 + (lane>>4), feature = lane&15 ----
    const int   kf   = lane & 15;
    const int   eoff = lane >> 4;
    const float ck   = centers[kf];
    const int   c0   = min(base0, CAP);
    const int   c1   = min(base1, CAP);
    float f0 = 0.0f, f1 = 0.0f;
    for (int e0 = 0; e0 < c0; e0 += 4) {
        const int e = e0 + eoff;
        if (e < c0) {
            const float d = sdist[wave][0][e];
            const float w = 0.5f * (1.0f + __cosf(d * PI_OVER_CUTOFF));
            const float t = d - ck;
            f0 += w * __expf(-(t * t) * INV_2ETA2);
        }
    }
    for (int e0 = 0; e0 < c1; e0 += 4) {
        const int e = e0 + eoff;
        if (e < c1) {
            const float d = sdist[wave][1][e];
            const float w = 0.5f * (1.0f + __cosf(d * PI_OVER_CUTOFF));
            const float t = d - ck;
            f1 += w * __expf(-(t * t) * INV_2ETA2);
        }
    }
    f0 += __shfl_xor(f0, 16, 64);  f0 += __shfl_xor(f0, 32, 64);
    f1 += __shfl_xor(f1, 16, 64);  f1 += __shfl_xor(f1, 32, 64);

    // ---- per-wave MLP, one atom at a time (lane = hidden unit) ----
    float e_at[2];
#pragma unroll
    for (int a = 0; a < 2; ++a) {
        const float facc = (a == 0) ? f0 : f1;
        float h = b1[lane];
#pragma unroll
        for (int k = 0; k < NRBF; ++k)
            h += __shfl(facc, k, 64) * W1[k * NHID + lane];  // broadcast feat[k]
        h = h / (1.0f + __expf(-h));    // silu
        s_h1[wave][lane] = h;           // within-wave producer/consumer: program order
        float h2 = b2[lane];
#pragma unroll 8
        for (int m = 0; m < NHID; ++m) h2 += s_h1[wave][m] * W2[m * NHID + lane];
        h2 = h2 / (1.0f + __expf(-h2)); // silu
        float e = h2 * W3[lane];
#pragma unroll
        for (int off = 32; off > 0; off >>= 1) e += __shfl_xor(e, off, 64);
        e_at[a] = e;
    }
    if (lane == 0) { s_e[wave][0] = e_at[0]; s_e[wave][1] = e_at[1]; }
    __syncthreads();
    if (tid == 0) {
        float s = 0.0f;
#pragma unroll
        for (int w = 0; w < 4; ++w) s += s_e[w][0] + s_e[w][1];
        ws[blockIdx.x] = s;
    }
}

// Sum 512 per-block energies + NATOMS*b3 -> out[0]. One wave.
__global__ __launch_bounds__(64) void reduce_kernel(
    const float* __restrict__ ws, const float* __restrict__ b3,
    float* __restrict__ out)
{
    const int lane = threadIdx.x;
    const float4 v0 = ((const float4*)ws)[lane];
    const float4 v1 = ((const float4*)ws)[lane + 64];
    float s = v0.x + v0.y + v0.z + v0.w + v1.x + v1.y + v1.z + v1.w;
#pragma unroll
    for (int off = 32; off > 0; off >>= 1) s += __shfl_xor(s, off, 64);
    if (lane == 0) out[0] = s + (float)NATOMS * b3[0];
}

extern "C" void kernel_launch(void* const* d_in, const int* in_sizes, int n_in,
                              void* d_out, int out_size, void* d_ws, size_t ws_size,
                              hipStream_t stream) {
    const float* pos     = (const float*)d_in[0];
    const float* centers = (const float*)d_in[1];
    const float* W1      = (const float*)d_in[2];
    const float* b1      = (const float*)d_in[3];
    const float* W2      = (const float*)d_in[4];
    const float* b2      = (const float*)d_in[5];
    const float* W3      = (const float*)d_in[6];
    const float* b3      = (const float*)d_in[7];
    float* out = (float*)d_out;
    float* ws  = (float*)d_ws;   // 512 floats of per-block energy

    hipLaunchKernelGGL(short_range_kernel, dim3(NATOMS / 8), dim3(256), 0, stream,
                       pos, centers, W1, b1, W2, b2, W3, ws);
    hipLaunchKernelGGL(reduce_kernel, dim3(1), dim3(64), 0, stream,
                       ws, b3, out);
}

// Round 8
// 82.860 us; speedup vs baseline: 1.0449x; 1.0449x over previous
//
#include <hip/hip_runtime.h>
#include <math.h>

#define NATOMS   4096
#define NRBF     16
#define NHID     64
#define CUTOFF2  25.0f
// ETA = 0.5*(5.0-0.5)/16 = 0.140625 ; 1/(2*ETA^2)
#define INV_2ETA2 25.283950617283951f
#define PI_OVER_CUTOFF 0.62831853071795865f  // pi / 5
#define CHUNK    1024   // atoms per LDS chunk
#define CAP      96     // per-wave neighbor capacity (mean ~33, >8 sigma)

// FINAL (r6 revert — best measured: 83.4 us total; r7's whole-array staging
// regressed to 86.6). Block = 4 waves = 4 atoms; j-loop over 4 SoA LDS
// chunks (sx/sy/sz, 12 KB -> 3 blocks/CU). Staging: thread t loads 3
// float4 = 4 whole atoms, register unpack, 3x ds_write_b128. Sieve: lane
// processes 4 atoms/iter via 3x ds_read_b128; ballot+prefix compaction
// (no atomics — 4096 same-address atomicAdds were the r1-r4 ~66 us floor).
// Dense transposed RBF (lane -> entry,feature; 1 exp/lane); per-wave MLP
// (lane = hidden unit); per-block sum -> ws[bid]; tiny reduce -> out[0].
__global__ __launch_bounds__(256) void short_range_kernel(
    const float* __restrict__ pos,
    const float* __restrict__ centers,
    const float* __restrict__ W1, const float* __restrict__ b1,
    const float* __restrict__ W2, const float* __restrict__ b2,
    const float* __restrict__ W3,
    float* __restrict__ ws)
{
    __shared__ float spos[3 * CHUNK];   // sx | sy | sz, 12 KB
    __shared__ float sdist[4][CAP];     // 1.5 KB
    __shared__ float s_h1[4][NHID];     // 1 KB
    __shared__ float s_part[4];

    const int tid  = threadIdx.x;
    const int lane = tid & 63;
    const int wave = tid >> 6;
    const int i    = blockIdx.x * 4 + wave;   // this wave's atom

    float* sx = spos;
    float* sy = spos + CHUNK;
    float* sz = spos + 2 * CHUNK;

    const float xi = pos[3 * i + 0];
    const float yi = pos[3 * i + 1];
    const float zi = pos[3 * i + 2];

    int base = 0;
    for (int c = 0; c < 4; ++c) {
        // ---- stage chunk c as SoA: thread t owns atoms 4t..4t+3 ----
        {
            const float4* src = (const float4*)(pos + c * (3 * CHUNK));
            const float4 v0 = src[3 * tid + 0];  // x0 y0 z0 x1
            const float4 v1 = src[3 * tid + 1];  // y1 z1 x2 y2
            const float4 v2 = src[3 * tid + 2];  // z2 x3 y3 z3
            *(float4*)&sx[4 * tid] = make_float4(v0.x, v0.w, v1.z, v2.y);
            *(float4*)&sy[4 * tid] = make_float4(v0.y, v1.x, v1.w, v2.z);
            *(float4*)&sz[4 * tid] = make_float4(v0.z, v1.y, v2.x, v2.w);
        }
        __syncthreads();

        // ---- sieve chunk: lane handles atoms a..a+3 per iter ----
#pragma unroll
        for (int it = 0; it < 4; ++it) {
            const int a = it * 256 + lane * 4;
            const float4 vx = *(const float4*)&sx[a];
            const float4 vy = *(const float4*)&sy[a];
            const float4 vz = *(const float4*)&sz[a];
#pragma unroll
            for (int u = 0; u < 4; ++u) {
                const float dx = ((const float*)&vx)[u] - xi;
                const float dy = ((const float*)&vy)[u] - yi;
                const float dz = ((const float*)&vz)[u] - zi;
                const float sq = dx * dx + dy * dy + dz * dz;
                const bool pass = (sq > 0.0f) && (sq < CUTOFF2);
                const unsigned long long mask = __ballot(pass);
                if (pass) {
                    const int slot = base + (int)__popcll(mask & ((1ull << lane) - 1ull));
                    if (slot < CAP) sdist[wave][slot] = sqrtf(sq);
                }
                base += (int)__popcll(mask);
            }
        }
        __syncthreads();   // before overwriting spos with next chunk
    }
    const int count = min(base, CAP);

    // ---- dense RBF, transposed: entry = e0 + (lane>>4), feature = lane&15 ----
    const int   kf   = lane & 15;
    const int   eoff = lane >> 4;
    const float ck   = centers[kf];
    float acc = 0.0f;
    for (int e0 = 0; e0 < count; e0 += 4) {
        const int e = e0 + eoff;
        if (e < count) {
            const float d = sdist[wave][e];
            const float w = 0.5f * (1.0f + __cosf(d * PI_OVER_CUTOFF));
            const float t = d - ck;
            acc += w * __expf(-(t * t) * INV_2ETA2);
        }
    }
    // fold 4 entry-groups: every lane ends with feature sum for (lane&15)
    acc += __shfl_xor(acc, 16, 64);
    acc += __shfl_xor(acc, 32, 64);

    // ---- per-wave MLP: lane n owns hidden unit n (NHID == 64) ----
    float h = b1[lane];
#pragma unroll
    for (int k = 0; k < NRBF; ++k)
        h += __shfl(acc, k, 64) * W1[k * NHID + lane];   // broadcast feat[k]
    h = h / (1.0f + __expf(-h));         // silu
    s_h1[wave][lane] = h;
    // single-wave producer/consumer on own LDS row: program order suffices
    float h2 = b2[lane];
#pragma unroll 8
    for (int m = 0; m < NHID; ++m) h2 += s_h1[wave][m] * W2[m * NHID + lane];
    h2 = h2 / (1.0f + __expf(-h2));      // silu
    float e = h2 * W3[lane];
#pragma unroll
    for (int off = 32; off > 0; off >>= 1) e += __shfl_xor(e, off, 64);
    if (lane == 0) s_part[wave] = e;
    __syncthreads();
    if (tid == 0)
        ws[blockIdx.x] = s_part[0] + s_part[1] + s_part[2] + s_part[3];
}

// Sum 1024 per-block energies + NATOMS*b3 -> out[0]. One block.
__global__ __launch_bounds__(256) void reduce_kernel(
    const float* __restrict__ ws, const float* __restrict__ b3,
    float* __restrict__ out)
{
    __shared__ float s_part[4];
    const int tid  = threadIdx.x;
    const int lane = tid & 63;
    const int wave = tid >> 6;

    const float4 v = ((const float4*)ws)[tid];   // 256 float4 = 1024 floats
    float s = v.x + v.y + v.z + v.w;
#pragma unroll
    for (int off = 32; off > 0; off >>= 1) s += __shfl_xor(s, off, 64);
    if (lane == 0) s_part[wave] = s;
    __syncthreads();
    if (tid == 0)
        out[0] = s_part[0] + s_part[1] + s_part[2] + s_part[3]
               + (float)NATOMS * b3[0];
}

extern "C" void kernel_launch(void* const* d_in, const int* in_sizes, int n_in,
                              void* d_out, int out_size, void* d_ws, size_t ws_size,
                              hipStream_t stream) {
    const float* pos     = (const float*)d_in[0];
    const float* centers = (const float*)d_in[1];
    const float* W1      = (const float*)d_in[2];
    const float* b1      = (const float*)d_in[3];
    const float* W2      = (const float*)d_in[4];
    const float* b2      = (const float*)d_in[5];
    const float* W3      = (const float*)d_in[6];
    const float* b3      = (const float*)d_in[7];
    float* out = (float*)d_out;
    float* ws  = (float*)d_ws;   // 1024 floats of per-block energy

    hipLaunchKernelGGL(short_range_kernel, dim3(NATOMS / 4), dim3(256), 0, stream,
                       pos, centers, W1, b1, W2, b2, W3, ws);
    hipLaunchKernelGGL(reduce_kernel, dim3(1), dim3(256), 0, stream,
                       ws, b3, out);
}